// Round 2
// baseline (64928.503 us; speedup 1.0000x reference)
//
#include <hip/hip_runtime.h>
#include <hip/hip_cooperative_groups.h>
#include <math.h>

namespace cg = cooperative_groups;

namespace {
constexpr int BATCH = 128;
constexpr int SEQ   = 512;
constexpr int EMBD  = 512;
constexpr int NL    = 32;
constexpr int BOSTAG = 1;
constexpr int EOSTAG = 2;
}

// hbuf layout: [2 parity][2 dir][512 u][128 b]  (65536 floats per (par,dir))
__global__ __launch_bounds__(512, 2)
void bilstm_coop(const int* __restrict__ x,
                 const float* __restrict__ emb,
                 const float* __restrict__ Wih_f, const float* __restrict__ Whh_f, const float* __restrict__ bf,
                 const float* __restrict__ Wih_b, const float* __restrict__ Whh_b, const float* __restrict__ bbias,
                 const float* __restrict__ Wout, const float* __restrict__ bout,
                 float* __restrict__ hbuf, float* __restrict__ em)
{
  cg::grid_group grid = cg::this_grid();
  __shared__ float4 inT4[2 * 1024];   // [buf][k(64)][slot(16)] swizzled: slot = b4 ^ (k&15)
  __shared__ float4 Wt4[2 * 512];     // [buf][k(64)][slot(8)]  swizzled: slot = r4 ^ (k&7)
  __shared__ float  WoutT[512 * 32];  // [k][l]
  __shared__ float  g_lds[32 * 64];   // [row][b]
  __shared__ float  em_red[16 * 32];  // [ks][l]
  __shared__ float  hcol[512];
  float* inTf = (float*)inT4;
  float* Wtf  = (float*)Wt4;

  const int tid = threadIdx.x, bi = blockIdx.x;
  const int dir = bi >> 7, bidx = bi & 127;
  const int ug = bidx >> 1, bh = bidx & 1;
  const int u0 = ug * 8, b_base = bh * 64;
  const int bb = bh * 64 + ug, bb_loc = ug;      // emission batch (global, block-local)

  const float* Wih = dir ? Wih_b : Wih_f;
  const float* Whh = dir ? Whh_b : Whh_f;
  const float* bv  = dir ? bbias : bf;

  // one-time: stage Wout slice transposed [k][l]; zero parity-1 h
  for (int l = 0; l < 32; ++l)
    WoutT[tid * 32 + l] = Wout[l * 1024 + dir * 512 + tid];
  hbuf[131072 + bi * 512 + tid] = 0.f;

  // compute mapping: kh = k-split lane, 8x8 micro-tile at (r0, b0)
  const int kh  = tid & 15;
  const int b_t = (tid >> 4) & 7, r_t = tid >> 7;
  const int b0 = b_t * 8, r0 = r_t * 8;
  const int slA0 = (2 * b_t) ^ kh,     slA1 = (2 * b_t + 1) ^ kh;
  const int slW0 = (2 * r_t) ^ (kh & 7), slW1 = (2 * r_t + 1) ^ (kh & 7);
  // staging mappings
  const int sb = tid >> 3, skg = tid & 7;        // emb: batch, k-group of 8
  const int hk = tid >> 3, hbq = tid & 7;        // h: k-row, b-group of 8
  const int wr = tid >> 4, wkg = tid & 15;       // W: row, k-group of 4
  const int w_grow = (wr >> 3) * 512 + u0 + (wr & 7);
  const float* WihRow = Wih + (size_t)w_grow * 512;
  const float* WhhRow = Whh + (size_t)w_grow * 512;
  // emission mapping
  const int el = tid & 31, eks = tid >> 5;
  // state-update mapping
  const int uu_s = tid >> 6, b_s = tid & 63;
  float biasg[4];
  #pragma unroll
  for (int g = 0; g < 4; ++g) biasg[g] = bv[g * 512 + u0 + uu_s];
  float cstate = 0.f;

  grid.sync();

  for (int s = 0; s < SEQ; ++s) {
    const int t = dir ? (SEQ - 1 - s) : s;
    const float* hprev = hbuf + (size_t)(((s + 1) & 1) * 2 + dir) * 65536;
    float*       hout  = hbuf + (size_t)((s & 1) * 2 + dir) * 65536;
    const int xid = x[(b_base + sb) * SEQ + t];
    const float* embrow = emb + (size_t)xid * EMBD;

    // ---- stage chunk 0 (emb cols 0..63) ----
    {
      float prf[8], pwf[4];
      *(float4*)&prf[0] = *(const float4*)&embrow[skg * 8];
      *(float4*)&prf[4] = *(const float4*)&embrow[skg * 8 + 4];
      *(float4*)&pwf[0] = *(const float4*)&WihRow[wkg * 4];
      #pragma unroll
      for (int i = 0; i < 8; ++i) { const int kk = skg * 8 + i;
        inTf[kk * 64 + (((sb >> 2) ^ (kk & 15)) << 2) + (sb & 3)] = prf[i]; }
      #pragma unroll
      for (int i = 0; i < 4; ++i) { const int kk = wkg * 4 + i;
        Wtf[kk * 32 + (((wr >> 2) ^ (kk & 7)) << 2) + (wr & 3)] = pwf[i]; }
    }
    __syncthreads();

    float acc[8][8];
    #pragma unroll
    for (int r = 0; r < 8; ++r)
      #pragma unroll
      for (int q = 0; q < 8; ++q) acc[r][q] = 0.f;
    float emP = 0.f;

    for (int c = 0; c < 16; ++c) {
      const int buf = c & 1;
      float nr[8], nw[4];
      if (c < 15) {                      // issue next-chunk global loads early
        const int cn = c + 1;
        if (cn < 8) {
          *(float4*)&nr[0] = *(const float4*)&embrow[cn * 64 + skg * 8];
          *(float4*)&nr[4] = *(const float4*)&embrow[cn * 64 + skg * 8 + 4];
          *(float4*)&nw[0] = *(const float4*)&WihRow[cn * 64 + wkg * 4];
        } else {
          const float* hsrc = hprev + (size_t)((cn - 8) * 64 + hk) * BATCH + b_base + hbq * 8;
          *(float4*)&nr[0] = *(const float4*)&hsrc[0];
          *(float4*)&nr[4] = *(const float4*)&hsrc[4];
          *(float4*)&nw[0] = *(const float4*)&WhhRow[(cn - 8) * 64 + wkg * 4];
        }
      }
      // ---- compute on buf ----
      const float4* iB = inT4 + buf * 1024;
      const float4* wB = Wt4 + buf * 512;
      #pragma unroll
      for (int j = 0; j < 4; ++j) {
        const int k = kh + 16 * j;
        const float4 a0 = iB[k * 16 + slA0];
        const float4 a1 = iB[k * 16 + slA1];
        const float4 w0 = wB[k * 8 + slW0];
        const float4 w1 = wB[k * 8 + slW1];
        const float af[8] = {a0.x, a0.y, a0.z, a0.w, a1.x, a1.y, a1.z, a1.w};
        const float wf[8] = {w0.x, w0.y, w0.z, w0.w, w1.x, w1.y, w1.z, w1.w};
        #pragma unroll
        for (int r = 0; r < 8; ++r)
          #pragma unroll
          for (int q = 0; q < 8; ++q)
            acc[r][q] = fmaf(wf[r], af[q], acc[r][q]);
      }
      // ---- emission partial from staged h (broadcast reads) ----
      if (s > 0 && c >= 8) {
        const float* ibf = inTf + buf * 4096;
        #pragma unroll
        for (int i = 0; i < 4; ++i) {
          const int kk = eks * 4 + i;
          const float hv = ibf[kk * 64 + (((bb_loc >> 2) ^ (kk & 15)) << 2) + (bb_loc & 3)];
          emP = fmaf(hv, WoutT[((c - 8) * 64 + kk) * 32 + el], emP);
        }
      }
      // ---- write next chunk into other buffer ----
      if (c < 15) {
        const int nb = (c + 1) & 1;
        if (c + 1 < 8) {
          float* of = inTf + nb * 4096;
          #pragma unroll
          for (int i = 0; i < 8; ++i) { const int kk = skg * 8 + i;
            of[kk * 64 + (((sb >> 2) ^ (kk & 15)) << 2) + (sb & 3)] = nr[i]; }
        } else {
          float4* o4 = inT4 + nb * 1024;
          const int s0_ = (hbq * 2) ^ (hk & 15), s1_ = (hbq * 2 + 1) ^ (hk & 15);
          o4[hk * 16 + s0_] = *(float4*)&nr[0];
          o4[hk * 16 + s1_] = *(float4*)&nr[4];
        }
        float* wfp = Wtf + nb * 2048;
        #pragma unroll
        for (int i = 0; i < 4; ++i) { const int kk = wkg * 4 + i;
          wfp[kk * 32 + (((wr >> 2) ^ (kk & 7)) << 2) + (wr & 3)] = nw[i]; }
        __syncthreads();
      }
    }

    // ---- butterfly reduce over the 16 kh lanes ----
    #pragma unroll
    for (int m = 1; m < 16; m <<= 1)
      #pragma unroll
      for (int r = 0; r < 8; ++r)
        #pragma unroll
        for (int q = 0; q < 8; ++q)
          acc[r][q] += __shfl_xor(acc[r][q], m, 64);
    // lane kh writes rows kh&7, batch-quad kh>>3
    {
      const int rr = kh & 7, qq = kh >> 3;
      const float4 gv = make_float4(acc[rr][qq * 4], acc[rr][qq * 4 + 1],
                                    acc[rr][qq * 4 + 2], acc[rr][qq * 4 + 3]);
      *(float4*)&g_lds[(r0 + rr) * 64 + b0 + qq * 4] = gv;
    }
    if (s > 0) em_red[eks * 32 + el] = emP;
    __syncthreads();

    // ---- gate nonlinearity + state update ----
    {
      const float gi = g_lds[(0 * 8 + uu_s) * 64 + b_s] + biasg[0];
      const float gf = g_lds[(1 * 8 + uu_s) * 64 + b_s] + biasg[1];
      const float gg = g_lds[(2 * 8 + uu_s) * 64 + b_s] + biasg[2];
      const float go = g_lds[(3 * 8 + uu_s) * 64 + b_s] + biasg[3];
      const float si = 1.f / (1.f + expf(-gi));
      const float sf = 1.f / (1.f + expf(-gf));
      const float so = 1.f / (1.f + expf(-go));
      cstate = sf * cstate + si * tanhf(gg);
      hout[(size_t)(u0 + uu_s) * BATCH + b_base + b_s] = so * tanhf(cstate);
    }
    // ---- emission write for step s-1 ----
    if (s > 0 && tid < 32) {
      float p = 0.f;
      #pragma unroll
      for (int ksi = 0; ksi < 16; ++ksi) p += em_red[ksi * 32 + tid];
      const int te = dir ? (SEQ - s) : (s - 1);
      const bool first = dir ? (te >= 256) : (te < 256);
      float* dst = em + ((size_t)bb * SEQ + te) * NL + tid;
      if (first) *dst = p + bout[tid];
      else       *dst = *dst + p;
    }
    grid.sync();
  }

  // ---- final emission for the last h (written at s=511, parity 1) ----
  {
    const float* hlast = hbuf + (size_t)(1 * 2 + dir) * 65536;
    hcol[tid] = hlast[(size_t)tid * BATCH + bb];
    __syncthreads();
    float emP = 0.f;
    #pragma unroll 4
    for (int i = 0; i < 32; ++i) {
      const int k = eks * 32 + i;
      emP = fmaf(hcol[k], WoutT[k * 32 + el], emP);
    }
    em_red[eks * 32 + el] = emP;
    __syncthreads();
    if (tid < 32) {
      float p = 0.f;
      #pragma unroll
      for (int ksi = 0; ksi < 16; ++ksi) p += em_red[ksi * 32 + tid];
      const int te = dir ? 0 : (SEQ - 1);
      float* dst = em + ((size_t)bb * SEQ + te) * NL + tid;
      *dst = *dst + p;
    }
  }
}

__global__ __launch_bounds__(64)
void viterbi_kernel(const float* __restrict__ em, const int* __restrict__ mask,
                    const float* __restrict__ trans, float* __restrict__ out)
{
  __shared__ float tr[32][33];
  __shared__ float alpha[32];
  __shared__ float fin[32];
  __shared__ unsigned char bp[SEQ][32];
  __shared__ float path[SEQ];

  const int b = blockIdx.x, tid = threadIdx.x;
  for (int i = tid; i < 1024; i += 64) tr[i >> 5][i & 31] = trans[i];
  __syncthreads();

  const float* emB = em + (size_t)b * SEQ * NL;
  if (tid < 32) alpha[tid] = tr[BOSTAG][tid] + emB[tid];
  __syncthreads();

  for (int t = 1; t < SEQ; ++t) {
    float best = -INFINITY, e = 0.f;
    int arg = 0;
    if (tid < 32) {
      e = emB[t * NL + tid];
      #pragma unroll 4
      for (int p = 0; p < 32; ++p) {
        const float sc = (alpha[p] + tr[p][tid]) + e;  // np broadcast order
        if (sc > best) { best = sc; arg = p; }          // first-occurrence argmax
      }
    }
    __syncthreads();
    if (tid < 32) {
      const float m = (float)mask[b * SEQ + t];
      alpha[tid] = m * best + (1.f - m) * alpha[tid];
      bp[t][tid] = (unsigned char)arg;
    }
    __syncthreads();
  }

  if (tid < 32) fin[tid] = alpha[tid] + tr[tid][EOSTAG];
  __syncthreads();

  if (tid == 0) {
    float best = fin[0]; int tag = 0;
    for (int n = 1; n < 32; ++n) if (fin[n] > best) { best = fin[n]; tag = n; }
    out[b] = best;
    path[SEQ - 1] = (float)tag;
    for (int k = SEQ - 2; k >= 0; --k) {
      const int prev = bp[k + 1][tag];
      if (mask[b * SEQ + k + 1] > 0) tag = prev;
      path[k] = (float)tag;
    }
  }
  __syncthreads();
  for (int idx = tid; idx < SEQ; idx += 64)
    out[BATCH + (size_t)b * SEQ + idx] = path[idx];
}

extern "C" void kernel_launch(void* const* d_in, const int* in_sizes, int n_in,
                              void* d_out, int out_size, void* d_ws, size_t ws_size,
                              hipStream_t stream) {
  (void)in_sizes; (void)n_in; (void)out_size; (void)ws_size;
  const int*   x     = (const int*)d_in[0];
  const int*   mask  = (const int*)d_in[1];
  const float* emb   = (const float*)d_in[2];
  const float* Wih_f = (const float*)d_in[3];
  const float* Whh_f = (const float*)d_in[4];
  const float* bf    = (const float*)d_in[5];
  const float* Wih_b = (const float*)d_in[6];
  const float* Whh_b = (const float*)d_in[7];
  const float* bb    = (const float*)d_in[8];
  const float* Wout  = (const float*)d_in[9];
  const float* bout  = (const float*)d_in[10];
  const float* trans = (const float*)d_in[11];
  float* out  = (float*)d_out;
  float* hbuf = (float*)d_ws;                   // 262144 floats (1 MB)
  float* em   = hbuf + 2ull * 2 * 512 * BATCH;  // 2097152 floats (8 MB)

  void* args[] = { (void*)&x, (void*)&emb,
                   (void*)&Wih_f, (void*)&Whh_f, (void*)&bf,
                   (void*)&Wih_b, (void*)&Whh_b, (void*)&bb,
                   (void*)&Wout, (void*)&bout,
                   (void*)&hbuf, (void*)&em };
  hipLaunchCooperativeKernel((void*)bilstm_coop, dim3(256), dim3(512), args, 0, stream);
  viterbi_kernel<<<dim3(128), dim3(64), 0, stream>>>(em, mask, trans, out);
}

// Round 3
// 30717.676 us; speedup vs baseline: 2.1137x; 2.1137x over previous
//
#include <hip/hip_runtime.h>
#include <hip/hip_cooperative_groups.h>
#include <math.h>

namespace cg = cooperative_groups;

namespace {
constexpr int BATCH = 128;
constexpr int SEQ   = 512;
constexpr int EMBD  = 512;
constexpr int NL    = 32;
constexpr int BOSTAG = 1;
constexpr int EOSTAG = 2;
}

// hbuf layout: [2 parity][2 dir][512 u][128 b]  (65536 floats per (par,dir))
__global__ __launch_bounds__(512, 2)
void bilstm_coop(const int* __restrict__ x,
                 const float* __restrict__ emb,
                 const float* __restrict__ Wih_f, const float* __restrict__ Whh_f, const float* __restrict__ bf,
                 const float* __restrict__ Wih_b, const float* __restrict__ Whh_b, const float* __restrict__ bbias,
                 const float* __restrict__ Wout, const float* __restrict__ bout,
                 float* __restrict__ hbuf, float* __restrict__ em)
{
  cg::grid_group grid = cg::this_grid();
  __shared__ float4 WT4[1024 * 8];    // W slice: [k][slot4][gate], slot4 = uu ^ (k&7). 128 KB
  __shared__ float4 At4[2 * 512];     // A tile:  [buf][k(32)][b(64)]. 16 KB
  __shared__ float  em_red[512];      // emission reduce [eks(16)][l(32)]. 2 KB
  float* WT = (float*)WT4;
  float* At = (float*)At4;

  const int tid = threadIdx.x, bi = blockIdx.x;
  const int dir = bi >> 7, bidx = bi & 127;
  const int ug  = bidx >> 1, bh = bidx & 1;    // ug 0..63 (unit slice), bh 0..1 (batch half)
  const int u0  = ug * 8, b_base = bh * 64;
  const int bb  = b_base + ug;                 // emission batch owned by this block

  const float* Wih = dir ? Wih_b : Wih_f;
  const float* Whh = dir ? Whh_b : Whh_f;
  const float* bv  = dir ? bbias : bf;

  // ---- one-time: W slice -> LDS, transposed + float4-slot swizzled ----
  for (int idx = tid; idx < 32768; idx += 512) {
    const int k = idx & 1023, row = idx >> 10;     // row = uu*4 + gate (0..31)
    const int gate = row & 3, uu = row >> 2;
    const int grow = gate * 512 + u0 + uu;
    const float v = (k < 512) ? Wih[(size_t)grow * 512 + k]
                              : Whh[(size_t)grow * 512 + (k - 512)];
    WT[k * 32 + ((uu ^ (k & 7)) << 2) + gate] = v;
  }

  // compute mapping: K-split lane ks (in-wave), 8-row x 4-batch micro-tile
  const int ks  = tid & 7;
  const int b_g = (tid >> 3) & 15;
  const int r_g = tid >> 7;                        // 0..3 (unit pair)
  const int slotA = ((r_g * 2)     ^ ks) * 4;
  const int slotB = ((r_g * 2 + 1) ^ ks) * 4;
  // staging mappings
  const int b_st = tid & 63, kg_st = tid >> 6;     // emb: batch, k-group of 4
  const int hb4  = tid & 15, hk = tid >> 4;        // h: float4 batch-group, k-row
  // emission mapping
  const int el   = tid & 31, eks = tid >> 5;       // label, k-split (16)
  // epilogue mapping: this thread owns state (u0+uu_sel, b_base+b_sel)
  const int uu_sel = r_g * 2 + (ks >> 2);
  const int qsel   = ks & 3;
  const int b_sel  = b_g * 4 + qsel;

  float bias_g[4];
  #pragma unroll
  for (int g = 0; g < 4; ++g) bias_g[g] = bv[g * 512 + u0 + uu_sel];

  float wout_r[32];
  #pragma unroll
  for (int ch = 0; ch < 16; ++ch) {
    wout_r[ch * 2 + 0] = Wout[(size_t)el * 1024 + dir * 512 + ch * 32 + eks * 2 + 0];
    wout_r[ch * 2 + 1] = Wout[(size_t)el * 1024 + dir * 512 + ch * 32 + eks * 2 + 1];
  }
  float cstate = 0.f;

  // zero parity-1 h (initial state for s=0)
  hbuf[131072 + bi * 512 + tid] = 0.f;
  grid.sync();

  for (int s = 0; s < SEQ; ++s) {
    const int t = dir ? (SEQ - 1 - s) : s;
    const float* hprev = hbuf + (size_t)(((s + 1) & 1) * 2 + dir) * 65536;
    float*       hout  = hbuf + (size_t)(((s    ) & 1) * 2 + dir) * 65536;
    const int    xid   = x[(b_base + b_st) * SEQ + t];
    const float* embrow = emb + (size_t)xid * EMBD;

    // prologue: stage chunk 0 (emb k 0..31) into buf0
    {
      const float4 v = *(const float4*)&embrow[kg_st * 4];
      At[(kg_st * 4 + 0) * 64 + b_st] = v.x;
      At[(kg_st * 4 + 1) * 64 + b_st] = v.y;
      At[(kg_st * 4 + 2) * 64 + b_st] = v.z;
      At[(kg_st * 4 + 3) * 64 + b_st] = v.w;
    }
    __syncthreads();

    float acc[8][4];
    #pragma unroll
    for (int r = 0; r < 8; ++r)
      #pragma unroll
      for (int q = 0; q < 4; ++q) acc[r][q] = 0.f;
    float emP = 0.f;

    // ---- emb chunks 0..15 ----
    for (int c = 0; c < 16; ++c) {
      float4 pre;
      if (c < 15)
        pre = *(const float4*)&embrow[(c + 1) * 32 + kg_st * 4];
      else
        pre = *(const float4*)&hprev[(size_t)hk * BATCH + b_base + hb4 * 4];
      const float* Acur = At + (c & 1) * 2048;
      #pragma unroll
      for (int i = 0; i < 4; ++i) {
        const int kl = ks + 8 * i;
        const float4 a4 = *(const float4*)&Acur[kl * 64 + b_g * 4];
        const float* Wk = WT + (c * 32 + kl) * 32;
        const float4 wA = *(const float4*)(Wk + slotA);
        const float4 wB = *(const float4*)(Wk + slotB);
        const float av[4] = {a4.x, a4.y, a4.z, a4.w};
        const float wa[4] = {wA.x, wA.y, wA.z, wA.w};
        const float wb[4] = {wB.x, wB.y, wB.z, wB.w};
        #pragma unroll
        for (int g = 0; g < 4; ++g)
          #pragma unroll
          for (int q = 0; q < 4; ++q) {
            acc[g][q]     = fmaf(wa[g], av[q], acc[g][q]);
            acc[4 + g][q] = fmaf(wb[g], av[q], acc[4 + g][q]);
          }
      }
      float* Anx = At + ((c + 1) & 1) * 2048;
      if (c < 15) {
        Anx[(kg_st * 4 + 0) * 64 + b_st] = pre.x;
        Anx[(kg_st * 4 + 1) * 64 + b_st] = pre.y;
        Anx[(kg_st * 4 + 2) * 64 + b_st] = pre.z;
        Anx[(kg_st * 4 + 3) * 64 + b_st] = pre.w;
      } else {
        *(float4*)&Anx[hk * 64 + hb4 * 4] = pre;
      }
      __syncthreads();
    }

    // ---- h chunks 16..31 (+ emission for h_{s-1}); unrolled for static wout idx ----
    #pragma unroll
    for (int c = 16; c < 32; ++c) {
      float4 pre;
      if (c < 31)
        pre = *(const float4*)&hprev[(size_t)((c - 15) * 32 + hk) * BATCH + b_base + hb4 * 4];
      const float* Acur = At + (c & 1) * 2048;
      #pragma unroll
      for (int i = 0; i < 4; ++i) {
        const int kl = ks + 8 * i;
        const float4 a4 = *(const float4*)&Acur[kl * 64 + b_g * 4];
        const float* Wk = WT + (c * 32 + kl) * 32;
        const float4 wA = *(const float4*)(Wk + slotA);
        const float4 wB = *(const float4*)(Wk + slotB);
        const float av[4] = {a4.x, a4.y, a4.z, a4.w};
        const float wa[4] = {wA.x, wA.y, wA.z, wA.w};
        const float wb[4] = {wB.x, wB.y, wB.z, wB.w};
        #pragma unroll
        for (int g = 0; g < 4; ++g)
          #pragma unroll
          for (int q = 0; q < 4; ++q) {
            acc[g][q]     = fmaf(wa[g], av[q], acc[g][q]);
            acc[4 + g][q] = fmaf(wb[g], av[q], acc[4 + g][q]);
          }
      }
      emP = fmaf(Acur[(eks * 2 + 0) * 64 + ug], wout_r[(c - 16) * 2 + 0], emP);
      emP = fmaf(Acur[(eks * 2 + 1) * 64 + ug], wout_r[(c - 16) * 2 + 1], emP);
      if (c < 31)
        *(float4*)&(At + ((c + 1) & 1) * 2048)[hk * 64 + hb4 * 4] = pre;
      __syncthreads();
    }

    // ---- butterfly reduce over the 8 ks lanes (in-wave) ----
    #pragma unroll
    for (int m = 1; m < 8; m <<= 1)
      #pragma unroll
      for (int r = 0; r < 8; ++r)
        #pragma unroll
        for (int q = 0; q < 4; ++q)
          acc[r][q] += __shfl_xor(acc[r][q], m, 64);

    // ---- gate nonlinearity + state update (register-only selection) ----
    {
      float g4[4];
      #pragma unroll
      for (int g = 0; g < 4; ++g) {
        const float lo = qsel == 0 ? acc[g][0]     : qsel == 1 ? acc[g][1]     : qsel == 2 ? acc[g][2]     : acc[g][3];
        const float hi = qsel == 0 ? acc[4 + g][0] : qsel == 1 ? acc[4 + g][1] : qsel == 2 ? acc[4 + g][2] : acc[4 + g][3];
        g4[g] = (ks >> 2) ? hi : lo;
      }
      const float gi = g4[0] + bias_g[0];
      const float gf = g4[1] + bias_g[1];
      const float gg = g4[2] + bias_g[2];
      const float go = g4[3] + bias_g[3];
      const float si = 1.f / (1.f + expf(-gi));
      const float sf = 1.f / (1.f + expf(-gf));
      const float so = 1.f / (1.f + expf(-go));
      cstate = sf * cstate + si * tanhf(gg);
      hout[(size_t)(u0 + uu_sel) * BATCH + b_base + b_sel] = so * tanhf(cstate);
    }

    // ---- emission write for step s-1 ----
    if (s > 0) em_red[eks * 32 + el] = emP;
    __syncthreads();
    if (s > 0 && tid < 32) {
      float p = 0.f;
      #pragma unroll
      for (int ksi = 0; ksi < 16; ++ksi) p += em_red[ksi * 32 + tid];
      const int te = dir ? (SEQ - s) : (s - 1);
      const bool first = dir ? (te >= 256) : (te < 256);
      float* dst = em + ((size_t)bb * SEQ + te) * NL + tid;
      if (first) *dst = p + bout[tid];
      else       *dst = *dst + p;
    }
    grid.sync();
  }

  // ---- tail emission for the last h (s=511, parity 1) ----
  {
    const float* hlast = hbuf + (size_t)(1 * 2 + dir) * 65536;
    float emP = 0.f;
    #pragma unroll
    for (int ch = 0; ch < 16; ++ch) {
      emP = fmaf(hlast[(size_t)(ch * 32 + eks * 2 + 0) * BATCH + bb], wout_r[ch * 2 + 0], emP);
      emP = fmaf(hlast[(size_t)(ch * 32 + eks * 2 + 1) * BATCH + bb], wout_r[ch * 2 + 1], emP);
    }
    em_red[eks * 32 + el] = emP;
    __syncthreads();
    if (tid < 32) {
      float p = 0.f;
      #pragma unroll
      for (int ksi = 0; ksi < 16; ++ksi) p += em_red[ksi * 32 + tid];
      const int te = dir ? 0 : (SEQ - 1);
      float* dst = em + ((size_t)bb * SEQ + te) * NL + tid;
      *dst = *dst + p;
    }
  }
}

__global__ __launch_bounds__(64)
void viterbi_kernel(const float* __restrict__ em, const int* __restrict__ mask,
                    const float* __restrict__ trans, float* __restrict__ out)
{
  __shared__ float tr[32][33];
  __shared__ float alpha[32];
  __shared__ float fin[32];
  __shared__ unsigned char bp[SEQ][32];
  __shared__ float path[SEQ];

  const int b = blockIdx.x, tid = threadIdx.x;
  for (int i = tid; i < 1024; i += 64) tr[i >> 5][i & 31] = trans[i];
  __syncthreads();

  const float* emB = em + (size_t)b * SEQ * NL;
  if (tid < 32) alpha[tid] = tr[BOSTAG][tid] + emB[tid];
  __syncthreads();

  for (int t = 1; t < SEQ; ++t) {
    float best = -INFINITY, e = 0.f;
    int arg = 0;
    if (tid < 32) {
      e = emB[t * NL + tid];
      #pragma unroll 4
      for (int p = 0; p < 32; ++p) {
        const float sc = (alpha[p] + tr[p][tid]) + e;  // np broadcast order
        if (sc > best) { best = sc; arg = p; }          // first-occurrence argmax
      }
    }
    __syncthreads();
    if (tid < 32) {
      const float m = (float)mask[b * SEQ + t];
      alpha[tid] = m * best + (1.f - m) * alpha[tid];
      bp[t][tid] = (unsigned char)arg;
    }
    __syncthreads();
  }

  if (tid < 32) fin[tid] = alpha[tid] + tr[tid][EOSTAG];
  __syncthreads();

  if (tid == 0) {
    float best = fin[0]; int tag = 0;
    for (int n = 1; n < 32; ++n) if (fin[n] > best) { best = fin[n]; tag = n; }
    out[b] = best;
    path[SEQ - 1] = (float)tag;
    for (int k = SEQ - 2; k >= 0; --k) {
      const int prev = bp[k + 1][tag];
      if (mask[b * SEQ + k + 1] > 0) tag = prev;
      path[k] = (float)tag;
    }
  }
  __syncthreads();
  for (int idx = tid; idx < SEQ; idx += 64)
    out[BATCH + (size_t)b * SEQ + idx] = path[idx];
}

extern "C" void kernel_launch(void* const* d_in, const int* in_sizes, int n_in,
                              void* d_out, int out_size, void* d_ws, size_t ws_size,
                              hipStream_t stream) {
  (void)in_sizes; (void)n_in; (void)out_size; (void)ws_size;
  const int*   x     = (const int*)d_in[0];
  const int*   mask  = (const int*)d_in[1];
  const float* emb   = (const float*)d_in[2];
  const float* Wih_f = (const float*)d_in[3];
  const float* Whh_f = (const float*)d_in[4];
  const float* bf    = (const float*)d_in[5];
  const float* Wih_b = (const float*)d_in[6];
  const float* Whh_b = (const float*)d_in[7];
  const float* bb    = (const float*)d_in[8];
  const float* Wout  = (const float*)d_in[9];
  const float* bout  = (const float*)d_in[10];
  const float* trans = (const float*)d_in[11];
  float* out  = (float*)d_out;
  float* hbuf = (float*)d_ws;                   // 262144 floats (1 MB)
  float* em   = hbuf + 2ull * 2 * 512 * BATCH;  // 2097152 floats (8 MB)

  void* args[] = { (void*)&x, (void*)&emb,
                   (void*)&Wih_f, (void*)&Whh_f, (void*)&bf,
                   (void*)&Wih_b, (void*)&Whh_b, (void*)&bb,
                   (void*)&Wout, (void*)&bout,
                   (void*)&hbuf, (void*)&em };
  hipLaunchCooperativeKernel((void*)bilstm_coop, dim3(256), dim3(512), args, 0, stream);
  viterbi_kernel<<<dim3(128), dim3(64), 0, stream>>>(em, mask, trans, out);
}